// Round 4
// baseline (106.680 us; speedup 1.0000x reference)
//
#include <hip/hip_runtime.h>
#include <hip/hip_bf16.h>

// Disable FMA contraction globally: the coordinate transform
// (p+1)*scale-0.5 must round exactly like numpy float32, or floor()
// can flip a cell index and change which octree keys we look up.
#pragma clang fp contract(off)

// Rank-structure geometry: keyspace <= 2^26 (depth<=8, B<=4).
// One block per 64 key values: {bits:u64, rank:u32, pad:u32} = 16B.
#define NBLKP (1 << 20)   // padded block count (exact for depth=8)
#define K_BITS 18         // fallback bucket bits (1 MB table)

typedef float f32x4 __attribute__((ext_vector_type(4)));

// Morton bit-spread of the low (up to 10) bits of v: bit d -> bit 3d.
// Bit-exact with the reference loop incl. negative / overflowed coords
// (two's complement low bits == the reference's per-bit (v>>d)&1).
__device__ __forceinline__ unsigned morton_spread(unsigned v) {
  v = (v | (v << 16)) & 0x030000FFu;
  v = (v | (v << 8)) & 0x0300F00Fu;
  v = (v | (v << 4)) & 0x030C30C3u;
  v = (v | (v << 2)) & 0x09249249u;
  return v;
}

__device__ __forceinline__ int morton_key(float xi, float yi, float zi,
                                          int gx, int gy, int gz, int b,
                                          int depth, unsigned cmask) {
  unsigned ux = ((unsigned)((int)xi + gx)) & cmask;
  unsigned uy = ((unsigned)((int)yi + gy)) & cmask;
  unsigned uz = ((unsigned)((int)zi + gz)) & cmask;
  return (int)((morton_spread(ux) << 2) | (morton_spread(uy) << 1) |
               morton_spread(uz)) | (b << (3 * depth));
}

// ---------------------------------------------------------------------------
// P1: prefill blockstart tab with H (tail/empty buckets = lower_bound past end)
// ---------------------------------------------------------------------------
__global__ __launch_bounds__(256) void octi_fill_tab(
    int* __restrict__ tab, int n, int H) {
  int j = blockIdx.x * 256 + threadIdx.x;
  if (j < n) tab[j] = H;
}

// ---------------------------------------------------------------------------
// P2: blockstart scatter: tab[b] = lower_bound(keys, b<<6).
// Thread m owns buckets (keys[m-1]>>6, keys[m]>>6]; disjoint, no atomics.
// ---------------------------------------------------------------------------
__global__ __launch_bounds__(256) void octi_scatter6(
    const int* __restrict__ keys, int H, int* __restrict__ tab) {
  int m = blockIdx.x * 256 + threadIdx.x;
  if (m >= H) return;
  int bc = (int)(((unsigned)keys[m]) >> 6);
  int bp = (m == 0) ? -1 : (int)(((unsigned)keys[m - 1]) >> 6);
  for (int j = bp + 1; j <= bc; ++j) tab[j] = m;
}

// ---------------------------------------------------------------------------
// P3: per-block presence bits + popcount (stashed in .z, scanned later).
// Padding blocks (depth<8) get start==end -> bits=0, pc=0: harmless.
// ---------------------------------------------------------------------------
__global__ __launch_bounds__(256) void octi_bits(
    const int* __restrict__ keys, const int* __restrict__ tab,
    uint4* __restrict__ blks) {
  int b = blockIdx.x * 256 + threadIdx.x;
  if (b >= NBLKP) return;
  int s = tab[b], e = tab[b + 1];
  unsigned long long bits = 0ull;
  for (int m = s; m < e; ++m)
    bits |= 1ull << (((unsigned)keys[m]) & 63u);
  blks[b] = make_uint4((unsigned)bits, (unsigned)(bits >> 32),
                       (unsigned)__popcll(bits), 0u);
}

// ---------------------------------------------------------------------------
// P4a: local exclusive scan of pc over 1024-block groups; group totals out.
// ---------------------------------------------------------------------------
__global__ __launch_bounds__(256) void octi_scan_a(
    uint4* __restrict__ blks, unsigned* __restrict__ gtot) {
  __shared__ unsigned sh[256];
  int g = blockIdx.x, t = threadIdx.x;
  int base = (g << 10) + (t << 2);
  unsigned pc[4], s = 0;
  #pragma unroll
  for (int j = 0; j < 4; ++j) { pc[j] = blks[base + j].z; s += pc[j]; }
  sh[t] = s;
  __syncthreads();
  for (int o = 1; o < 256; o <<= 1) {
    unsigned v = (t >= o) ? sh[t - o] : 0u;
    __syncthreads();
    sh[t] += v;
    __syncthreads();
  }
  unsigned run = sh[t] - s;  // exclusive prefix of this thread's 4
  if (t == 255) gtot[g] = sh[255];
  #pragma unroll
  for (int j = 0; j < 4; ++j) { unsigned p = pc[j]; blks[base + j].z = run; run += p; }
}

// ---------------------------------------------------------------------------
// P4b: single-block exclusive scan of the 1024 group totals.
// ---------------------------------------------------------------------------
__global__ __launch_bounds__(256) void octi_scan_b(
    const unsigned* __restrict__ gtot, unsigned* __restrict__ goff) {
  __shared__ unsigned sh[256];
  int t = threadIdx.x;
  int base = t << 2;
  unsigned v[4], s = 0;
  #pragma unroll
  for (int j = 0; j < 4; ++j) { v[j] = gtot[base + j]; s += v[j]; }
  sh[t] = s;
  __syncthreads();
  for (int o = 1; o < 256; o <<= 1) {
    unsigned x = (t >= o) ? sh[t - o] : 0u;
    __syncthreads();
    sh[t] += x;
    __syncthreads();
  }
  unsigned run = sh[t] - s;
  #pragma unroll
  for (int j = 0; j < 4; ++j) { goff[base + j] = run; run += v[j]; }
}

// ---------------------------------------------------------------------------
// P4c: add group offsets -> final rank per block.
// ---------------------------------------------------------------------------
__global__ __launch_bounds__(256) void octi_scan_c(
    uint4* __restrict__ blks, const unsigned* __restrict__ goff) {
  int b = blockIdx.x * 256 + threadIdx.x;
  if (b < NBLKP) blks[b].z += goff[b >> 10];
}

// ---------------------------------------------------------------------------
// P5: distinct-rank -> first occurrence row (searchsorted side=left result).
// ---------------------------------------------------------------------------
__global__ __launch_bounds__(256) void octi_fidx(
    const int* __restrict__ keys, int H, const uint4* __restrict__ blks,
    int* __restrict__ fidx) {
  int m = blockIdx.x * 256 + threadIdx.x;
  if (m >= H) return;
  int k = keys[m];
  if (m > 0 && keys[m - 1] == k) return;  // not first occurrence
  unsigned uk = (unsigned)k;
  uint4 B = blks[uk >> 6];
  unsigned long long bits = ((unsigned long long)B.y << 32) | B.x;
  int bit = (int)(uk & 63u);
  unsigned r = B.z + (unsigned)__popcll(bits & ((1ull << bit) - 1ull));
  fidx[r] = m;
}

// ---------------------------------------------------------------------------
// Main interpolation, C == 32 fast path.  8 lanes per point:
// lane = corner index (lookup phase) and channel-quad (gather/write phase).
// One 16B random load resolves present+rank; hits (~3%) do one more load.
// ---------------------------------------------------------------------------
__global__ __launch_bounds__(256) void octi_interp32(
    const float* __restrict__ data, const float* __restrict__ pts,
    const int* __restrict__ depth_ptr, const uint4* __restrict__ blks,
    const int* __restrict__ fidx, float* __restrict__ out, int N) {
  int t = blockIdx.x * 256 + threadIdx.x;
  int i = t >> 3;   // point index
  if (i >= N) return;
  int l = t & 7;    // corner / channel-quad index

  int depth = *depth_ptr;
  float scale = (float)(1 << (depth - 1));
  unsigned cmask = (1u << depth) - 1u;

  float4 p = reinterpret_cast<const float4*>(pts)[i];

  // exact numpy-f32 sequence: (p + 1.0f) * scale - 0.5f  (no contraction)
  float xf = (p.x + 1.0f) * scale - 0.5f;
  float yf = (p.y + 1.0f) * scale - 0.5f;
  float zf = (p.z + 1.0f) * scale - 0.5f;
  float xi = floorf(xf), yi = floorf(yf), zi = floorf(zf);
  float fx = xf - xi, fy = yf - yi, fz = zf - zi;

  // grid row order: corner = (gx<<2)|(gy<<1)|gz
  int gx = (l >> 2) & 1, gy = (l >> 1) & 1, gz = l & 1;
  int key = morton_key(xi, yi, zi, gx, gy, gz, (int)p.w, depth, cmask);

  // one 16B load resolves presence + rank
  unsigned uk = (unsigned)key;
  uint4 B = blks[uk >> 6];
  unsigned long long bits = ((unsigned long long)B.y << 32) | B.x;
  int bit = (int)(uk & 63u);
  bool present = (bits >> bit) & 1ull;
  int posc = 0;
  if (present) {
    unsigned r = B.z + (unsigned)__popcll(bits & ((1ull << bit) - 1ull));
    posc = fidx[r];
  }

  // trilinear weight |((1-gx)-fx)*((1-gy)-fy)*((1-gz)-fz)|
  float wx = (1.0f - (float)gx) - fx;
  float wy = (1.0f - (float)gy) - fy;
  float wz = (1.0f - (float)gz) - fz;
  float w = present ? fabsf((wx * wy) * wz) : 0.0f;

  // ballot-driven gather: only iterate corners that actually hit (~0.24/8)
  int lane = threadIdx.x & 63;
  int base = lane & 56;
  unsigned long long ball = __ballot(w != 0.0f);
  unsigned g8 = (unsigned)((ball >> base) & 0xFFull);
  float4 acc = make_float4(0.f, 0.f, 0.f, 0.f);
  float norm = 0.0f;
  while (g8) {
    int q = __ffs(g8) - 1;
    g8 &= g8 - 1;
    float wq = __shfl(w, base + q, 64);
    int   pq = __shfl(posc, base + q, 64);
    norm += wq;
    float4 f = reinterpret_cast<const float4*>(data)[pq * 8 + l];
    acc.x += wq * f.x;
    acc.y += wq * f.y;
    acc.z += wq * f.z;
    acc.w += wq * f.w;
  }
  float dnm = norm + 1e-12f;
  float4 o = make_float4(acc.x / dnm, acc.y / dnm, acc.z / dnm, acc.w / dnm);
  reinterpret_cast<float4*>(out)[i * 8 + l] = o;
}

// ---------------------------------------------------------------------------
// Fallback path (small ws or C != 32): bucketed binary search, one thread/point.
// ---------------------------------------------------------------------------
__global__ __launch_bounds__(256) void octi_scatter_k(
    const int* __restrict__ keys, int H, const int* __restrict__ depth_ptr,
    int* __restrict__ tab, int kbits) {
  int m = blockIdx.x * 256 + threadIdx.x;
  if (m >= H) return;
  int depth = *depth_ptr;
  int kb = 3 * depth + 2;
  int S = kb > kbits ? kb - kbits : 0;
  int bc = (int)(((unsigned)keys[m]) >> S);
  int bp = (m == 0) ? -1 : (int)(((unsigned)keys[m - 1]) >> S);
  for (int j = bp + 1; j <= bc; ++j) tab[j] = m;
}

__global__ __launch_bounds__(256) void octi_interp_gen(
    const float* __restrict__ data, const float* __restrict__ pts,
    const int* __restrict__ keys, const int* __restrict__ depth_ptr,
    const int* __restrict__ tab, float* __restrict__ out,
    int N, int H, int C, int kbits) {
  int i = blockIdx.x * 256 + threadIdx.x;
  if (i >= N) return;
  int depth = *depth_ptr;
  int kb = 3 * depth + 2;
  int S = kb > kbits ? kb - kbits : 0;
  float scale = (float)(1 << (depth - 1));
  unsigned cmask = (1u << depth) - 1u;
  const float4 p = reinterpret_cast<const float4*>(pts)[i];
  float xf = (p.x + 1.0f) * scale - 0.5f;
  float yf = (p.y + 1.0f) * scale - 0.5f;
  float zf = (p.z + 1.0f) * scale - 0.5f;
  float xi = floorf(xf), yi = floorf(yf), zi = floorf(zf);
  float fx = xf - xi, fy = yf - yi, fz = zf - zi;
  int b = (int)p.w;
  float wv[8]; int pv[8];
  float norm = 0.0f;
  for (int l = 0; l < 8; ++l) {
    int gx = (l >> 2) & 1, gy = (l >> 1) & 1, gz = l & 1;
    int key = morton_key(xi, yi, zi, gx, gy, gz, b, depth, cmask);
    unsigned bkt = ((unsigned)key) >> S;
    int lo = tab ? tab[bkt] : 0;
    int hi = tab ? tab[bkt + 1] : H;
    bool present = false; int posc = 0;
    if (lo < hi) {
      int hi0 = hi;
      while (lo < hi) { int mid = (lo + hi) >> 1; if (keys[mid] < key) lo = mid + 1; else hi = mid; }
      present = (lo < hi0) && (keys[lo] == key);
      posc = lo;
    }
    float wx = (1.0f - (float)gx) - fx;
    float wy = (1.0f - (float)gy) - fy;
    float wz = (1.0f - (float)gz) - fz;
    float w = present ? fabsf((wx * wy) * wz) : 0.0f;
    wv[l] = w; pv[l] = posc; norm += w;
  }
  float dnm = norm + 1e-12f;
  for (int c = 0; c < C; ++c) {
    float acc = 0.0f;
    for (int q = 0; q < 8; ++q)
      if (wv[q] != 0.0f) acc += wv[q] * data[(long long)pv[q] * C + c];
    out[(long long)i * C + c] = acc / dnm;
  }
}

extern "C" void kernel_launch(void* const* d_in, const int* in_sizes, int n_in,
                              void* d_out, int out_size, void* d_ws, size_t ws_size,
                              hipStream_t stream) {
  const float* data = (const float*)d_in[0];
  const float* pts  = (const float*)d_in[1];
  const int*   keys = (const int*)d_in[2];
  const int*   dep  = (const int*)d_in[3];
  float* out = (float*)d_out;

  int H = in_sizes[2];
  int N = in_sizes[1] / 4;
  int C = (H > 0) ? in_sizes[0] / H : 0;

  // workspace layout
  size_t off_blks = 0;                                   // 16 MB: uint4[NBLKP]
  size_t off_tab  = (size_t)NBLKP * 16;                  // 4 MB + 4: int[NBLKP+1]
  size_t off_gtot = off_tab + ((size_t)NBLKP + 1) * 4;
  off_gtot = (off_gtot + 255) & ~(size_t)255;
  size_t off_goff = off_gtot + 4096;
  size_t off_fidx = off_goff + 4096;
  size_t need = off_fidx + (size_t)H * 4;

  if (C == 32 && ws_size >= need) {
    uint4*    blks = (uint4*)((char*)d_ws + off_blks);
    int*      tab  = (int*)((char*)d_ws + off_tab);
    unsigned* gtot = (unsigned*)((char*)d_ws + off_gtot);
    unsigned* goff = (unsigned*)((char*)d_ws + off_goff);
    int*      fidx = (int*)((char*)d_ws + off_fidx);

    octi_fill_tab<<<(NBLKP + 1 + 255) / 256, 256, 0, stream>>>(tab, NBLKP + 1, H);
    octi_scatter6<<<(H + 255) / 256, 256, 0, stream>>>(keys, H, tab);
    octi_bits<<<NBLKP / 256, 256, 0, stream>>>(keys, tab, blks);
    octi_scan_a<<<1024, 256, 0, stream>>>(blks, gtot);
    octi_scan_b<<<1, 256, 0, stream>>>(gtot, goff);
    octi_scan_c<<<NBLKP / 256, 256, 0, stream>>>(blks, goff);
    octi_fidx<<<(H + 255) / 256, 256, 0, stream>>>(keys, H, blks, fidx);

    long long tt = (long long)N * 8;
    octi_interp32<<<(int)((tt + 255) / 256), 256, 0, stream>>>(
        data, pts, dep, blks, fidx, out, N);
  } else {
    // fallback: bucketed binary search
    int kbits = K_BITS;
    int NB1 = (1 << kbits) + 1;
    bool useTab = ws_size >= (size_t)NB1 * sizeof(int);
    int* tab = (int*)d_ws;
    if (useTab) {
      octi_fill_tab<<<(NB1 + 255) / 256, 256, 0, stream>>>(tab, NB1, H);
      octi_scatter_k<<<(H + 255) / 256, 256, 0, stream>>>(keys, H, dep, tab, kbits);
    }
    octi_interp_gen<<<(N + 255) / 256, 256, 0, stream>>>(
        data, pts, keys, dep, useTab ? tab : nullptr, out, N, H, C, kbits);
  }
}

// Round 5
// 79.050 us; speedup vs baseline: 1.3495x; 1.3495x over previous
//
#include <hip/hip_runtime.h>
#include <hip/hip_bf16.h>

// Disable FMA contraction globally: the coordinate transform
// (p+1)*scale-0.5 must round exactly like numpy float32, or floor()
// can flip a cell index and change which octree keys we look up.
#pragma clang fp contract(off)

// Keyspace <= 2^26 (depth=8, B=4). One block per 64 key values:
// {bits:u64, start:u32, pad} = 16B -> 1M blocks = 16 MB.
#define NBLKP (1 << 20)
#define K_BITS 18  // fallback bucket bits (1 MB table)

// Morton bit-spread of the low 8 bits of v: bit d -> bit 3d.
// Bit-exact with the reference loop incl. negative / overflowed coords
// (two's complement low bits == the reference's per-bit (v>>d)&1).
__device__ __forceinline__ unsigned morton_spread(unsigned v) {
  v = (v | (v << 16)) & 0x030000FFu;
  v = (v | (v << 8)) & 0x0300F00Fu;
  v = (v | (v << 4)) & 0x030C30C3u;
  v = (v | (v << 2)) & 0x09249249u;
  return v;
}

__device__ __forceinline__ int morton_key(float xi, float yi, float zi,
                                          int gx, int gy, int gz, int b,
                                          int depth, unsigned cmask) {
  unsigned ux = ((unsigned)((int)xi + gx)) & cmask;
  unsigned uy = ((unsigned)((int)yi + gy)) & cmask;
  unsigned uz = ((unsigned)((int)zi + gz)) & cmask;
  return (int)((morton_spread(ux) << 2) | (morton_spread(uy) << 1) |
               morton_spread(uz)) | (b << (3 * depth));
}

// ---------------------------------------------------------------------------
// P1: prefill start-tab with H (buckets past the last key = lower_bound end)
// ---------------------------------------------------------------------------
__global__ __launch_bounds__(256) void octi_fill_tab(
    int* __restrict__ tab, int n, int H) {
  int j = blockIdx.x * 256 + threadIdx.x;
  if (j < n) tab[j] = H;
}

// ---------------------------------------------------------------------------
// P2: tab[b] = lower_bound(keys, b<<6). Thread m owns buckets
// (keys[m-1]>>6, keys[m]>>6]  (thread 0: [0, keys[0]>>6]). Disjoint, no atomics.
// ---------------------------------------------------------------------------
__global__ __launch_bounds__(256) void octi_scatter6(
    const int* __restrict__ keys, int H, int* __restrict__ tab) {
  int m = blockIdx.x * 256 + threadIdx.x;
  if (m >= H) return;
  int bc = (int)(((unsigned)keys[m]) >> 6);
  int bp = (m == 0) ? -1 : (int)(((unsigned)keys[m - 1]) >> 6);
  for (int j = bp + 1; j <= bc; ++j) tab[j] = m;
}

// ---------------------------------------------------------------------------
// P3: pack {presence bits, start} per block. Empty blocks: bits=0.
// ---------------------------------------------------------------------------
__global__ __launch_bounds__(256) void octi_pack(
    const int* __restrict__ keys, const int* __restrict__ tab,
    uint4* __restrict__ blks) {
  int b = blockIdx.x * 256 + threadIdx.x;
  if (b >= NBLKP) return;
  int s = tab[b], e = tab[b + 1];
  unsigned long long bits = 0ull;
  for (int m = s; m < e; ++m)
    bits |= 1ull << (((unsigned)keys[m]) & 63u);
  blks[b] = make_uint4((unsigned)bits, (unsigned)(bits >> 32),
                       (unsigned)s, 0u);
}

// ---------------------------------------------------------------------------
// Main interpolation, C == 32 fast path.  8 lanes per group; each group
// handles TWO independent points (i, i+half) for memory-level parallelism.
// lane = corner index (lookup) and channel-quad (gather/write, float4).
// One 16B random load resolves presence; hits (~3%) scan <=1 extra line.
// ---------------------------------------------------------------------------
__global__ __launch_bounds__(256) void octi_interp32(
    const float* __restrict__ data, const float* __restrict__ pts,
    const int* __restrict__ keys, const int* __restrict__ depth_ptr,
    const uint4* __restrict__ blks, float* __restrict__ out,
    int N, int half) {
  int t = blockIdx.x * 256 + threadIdx.x;
  int g = t >> 3;
  if (g >= half) return;
  int l = t & 7;
  int i0 = g;
  int i1 = g + half;
  bool has1 = i1 < N;

  int depth = *depth_ptr;
  float scale = (float)(1 << (depth - 1));
  unsigned cmask = (1u << depth) - 1u;
  int gx = (l >> 2) & 1, gy = (l >> 1) & 1, gz = l & 1;

  // ---- phase A: coords + keys for both points, issue both blks loads ----
  float4 p0 = reinterpret_cast<const float4*>(pts)[i0];
  float4 p1 = reinterpret_cast<const float4*>(pts)[has1 ? i1 : i0];

  float xf0 = (p0.x + 1.0f) * scale - 0.5f;
  float yf0 = (p0.y + 1.0f) * scale - 0.5f;
  float zf0 = (p0.z + 1.0f) * scale - 0.5f;
  float xi0 = floorf(xf0), yi0 = floorf(yf0), zi0 = floorf(zf0);
  float fx0 = xf0 - xi0, fy0 = yf0 - yi0, fz0 = zf0 - zi0;
  int key0 = morton_key(xi0, yi0, zi0, gx, gy, gz, (int)p0.w, depth, cmask);

  float xf1 = (p1.x + 1.0f) * scale - 0.5f;
  float yf1 = (p1.y + 1.0f) * scale - 0.5f;
  float zf1 = (p1.z + 1.0f) * scale - 0.5f;
  float xi1 = floorf(xf1), yi1 = floorf(yf1), zi1 = floorf(zf1);
  float fx1 = xf1 - xi1, fy1 = yf1 - yi1, fz1 = zf1 - zi1;
  int key1 = morton_key(xi1, yi1, zi1, gx, gy, gz, (int)p1.w, depth, cmask);

  uint4 B0 = blks[(((unsigned)key0) >> 6) & (NBLKP - 1)];
  uint4 B1 = blks[(((unsigned)key1) >> 6) & (NBLKP - 1)];

  // ---- phase B: resolve presence + row for both ----
  unsigned long long bits0 = ((unsigned long long)B0.y << 32) | B0.x;
  bool present0 = (bits0 >> (key0 & 63)) & 1ull;
  int pos0 = 0;
  if (present0) {
    int row = (int)B0.z;
    while (keys[row] < key0) ++row;  // avg <2 steps, same line
    pos0 = row;
  }
  unsigned long long bits1 = ((unsigned long long)B1.y << 32) | B1.x;
  bool present1 = has1 && ((bits1 >> (key1 & 63)) & 1ull);
  int pos1 = 0;
  if (present1) {
    int row = (int)B1.z;
    while (keys[row] < key1) ++row;
    pos1 = row;
  }

  // ---- phase C: weights, ballot-driven gather, write ----
  int lane = threadIdx.x & 63;
  int base = lane & 56;

  float wx0 = (1.0f - (float)gx) - fx0;
  float wy0 = (1.0f - (float)gy) - fy0;
  float wz0 = (1.0f - (float)gz) - fz0;
  float w0 = present0 ? fabsf((wx0 * wy0) * wz0) : 0.0f;

  float wx1 = (1.0f - (float)gx) - fx1;
  float wy1 = (1.0f - (float)gy) - fy1;
  float wz1 = (1.0f - (float)gz) - fz1;
  float w1 = present1 ? fabsf((wx1 * wy1) * wz1) : 0.0f;

  unsigned long long ball0 = __ballot(w0 != 0.0f);
  unsigned long long ball1 = __ballot(w1 != 0.0f);

  {
    unsigned g8 = (unsigned)((ball0 >> base) & 0xFFull);
    float4 acc = make_float4(0.f, 0.f, 0.f, 0.f);
    float norm = 0.0f;
    while (g8) {
      int q = __ffs(g8) - 1;
      g8 &= g8 - 1;
      float wq = __shfl(w0, base + q, 64);
      int   pq = __shfl(pos0, base + q, 64);
      norm += wq;
      float4 f = reinterpret_cast<const float4*>(data)[pq * 8 + l];
      acc.x += wq * f.x;
      acc.y += wq * f.y;
      acc.z += wq * f.z;
      acc.w += wq * f.w;
    }
    float inv = 1.0f / (norm + 1e-12f);
    float4 o = make_float4(acc.x * inv, acc.y * inv, acc.z * inv, acc.w * inv);
    reinterpret_cast<float4*>(out)[i0 * 8 + l] = o;
  }
  if (has1) {
    unsigned g8 = (unsigned)((ball1 >> base) & 0xFFull);
    float4 acc = make_float4(0.f, 0.f, 0.f, 0.f);
    float norm = 0.0f;
    while (g8) {
      int q = __ffs(g8) - 1;
      g8 &= g8 - 1;
      float wq = __shfl(w1, base + q, 64);
      int   pq = __shfl(pos1, base + q, 64);
      norm += wq;
      float4 f = reinterpret_cast<const float4*>(data)[pq * 8 + l];
      acc.x += wq * f.x;
      acc.y += wq * f.y;
      acc.z += wq * f.z;
      acc.w += wq * f.w;
    }
    float inv = 1.0f / (norm + 1e-12f);
    float4 o = make_float4(acc.x * inv, acc.y * inv, acc.z * inv, acc.w * inv);
    reinterpret_cast<float4*>(out)[i1 * 8 + l] = o;
  }
}

// ---------------------------------------------------------------------------
// Fallback path (small ws or C != 32): bucketed binary search, one thread/point.
// ---------------------------------------------------------------------------
__global__ __launch_bounds__(256) void octi_scatter_k(
    const int* __restrict__ keys, int H, const int* __restrict__ depth_ptr,
    int* __restrict__ tab, int kbits) {
  int m = blockIdx.x * 256 + threadIdx.x;
  if (m >= H) return;
  int depth = *depth_ptr;
  int kb = 3 * depth + 2;
  int S = kb > kbits ? kb - kbits : 0;
  int bc = (int)(((unsigned)keys[m]) >> S);
  int bp = (m == 0) ? -1 : (int)(((unsigned)keys[m - 1]) >> S);
  for (int j = bp + 1; j <= bc; ++j) tab[j] = m;
}

__global__ __launch_bounds__(256) void octi_interp_gen(
    const float* __restrict__ data, const float* __restrict__ pts,
    const int* __restrict__ keys, const int* __restrict__ depth_ptr,
    const int* __restrict__ tab, float* __restrict__ out,
    int N, int H, int C, int kbits) {
  int i = blockIdx.x * 256 + threadIdx.x;
  if (i >= N) return;
  int depth = *depth_ptr;
  int kb = 3 * depth + 2;
  int S = kb > kbits ? kb - kbits : 0;
  float scale = (float)(1 << (depth - 1));
  unsigned cmask = (1u << depth) - 1u;
  const float4 p = reinterpret_cast<const float4*>(pts)[i];
  float xf = (p.x + 1.0f) * scale - 0.5f;
  float yf = (p.y + 1.0f) * scale - 0.5f;
  float zf = (p.z + 1.0f) * scale - 0.5f;
  float xi = floorf(xf), yi = floorf(yf), zi = floorf(zf);
  float fx = xf - xi, fy = yf - yi, fz = zf - zi;
  int b = (int)p.w;
  float wv[8]; int pv[8];
  float norm = 0.0f;
  for (int l = 0; l < 8; ++l) {
    int gx = (l >> 2) & 1, gy = (l >> 1) & 1, gz = l & 1;
    int key = morton_key(xi, yi, zi, gx, gy, gz, b, depth, cmask);
    unsigned bkt = ((unsigned)key) >> S;
    int lo = tab ? tab[bkt] : 0;
    int hi = tab ? tab[bkt + 1] : H;
    bool present = false; int posc = 0;
    if (lo < hi) {
      int hi0 = hi;
      while (lo < hi) { int mid = (lo + hi) >> 1; if (keys[mid] < key) lo = mid + 1; else hi = mid; }
      present = (lo < hi0) && (keys[lo] == key);
      posc = lo;
    }
    float wx = (1.0f - (float)gx) - fx;
    float wy = (1.0f - (float)gy) - fy;
    float wz = (1.0f - (float)gz) - fz;
    float w = present ? fabsf((wx * wy) * wz) : 0.0f;
    wv[l] = w; pv[l] = posc; norm += w;
  }
  float dnm = norm + 1e-12f;
  for (int c = 0; c < C; ++c) {
    float acc = 0.0f;
    for (int q = 0; q < 8; ++q)
      if (wv[q] != 0.0f) acc += wv[q] * data[(long long)pv[q] * C + c];
    out[(long long)i * C + c] = acc / dnm;
  }
}

extern "C" void kernel_launch(void* const* d_in, const int* in_sizes, int n_in,
                              void* d_out, int out_size, void* d_ws, size_t ws_size,
                              hipStream_t stream) {
  const float* data = (const float*)d_in[0];
  const float* pts  = (const float*)d_in[1];
  const int*   keys = (const int*)d_in[2];
  const int*   dep  = (const int*)d_in[3];
  float* out = (float*)d_out;

  int H = in_sizes[2];
  int N = in_sizes[1] / 4;
  int C = (H > 0) ? in_sizes[0] / H : 0;

  // workspace layout: blks (16 MB) + tab (4 MB + 4)
  size_t off_blks = 0;
  size_t off_tab  = (size_t)NBLKP * 16;
  size_t need = off_tab + ((size_t)NBLKP + 1) * 4;

  if (C == 32 && ws_size >= need) {
    uint4* blks = (uint4*)((char*)d_ws + off_blks);
    int*   tab  = (int*)((char*)d_ws + off_tab);

    octi_fill_tab<<<(NBLKP + 1 + 255) / 256, 256, 0, stream>>>(tab, NBLKP + 1, H);
    octi_scatter6<<<(H + 255) / 256, 256, 0, stream>>>(keys, H, tab);
    octi_pack<<<NBLKP / 256, 256, 0, stream>>>(keys, tab, blks);

    int half = (N + 1) >> 1;
    long long tt = (long long)half * 8;
    octi_interp32<<<(int)((tt + 255) / 256), 256, 0, stream>>>(
        data, pts, keys, dep, blks, out, N, half);
  } else {
    int kbits = K_BITS;
    int NB1 = (1 << kbits) + 1;
    bool useTab = ws_size >= (size_t)NB1 * sizeof(int);
    int* tab = (int*)d_ws;
    if (useTab) {
      octi_fill_tab<<<(NB1 + 255) / 256, 256, 0, stream>>>(tab, NB1, H);
      octi_scatter_k<<<(H + 255) / 256, 256, 0, stream>>>(keys, H, dep, tab, kbits);
    }
    octi_interp_gen<<<(N + 255) / 256, 256, 0, stream>>>(
        data, pts, keys, dep, useTab ? tab : nullptr, out, N, H, C, kbits);
  }
}